// Round 7
// baseline (105.720 us; speedup 1.0000x reference)
//
#include <hip/hip_runtime.h>

// GIB layer: B=2, N=65536, M=8192, K=32; 16 each of cy/cone/disk/ellip gibs;
// out = mean_k(gib_vals) @ lambdas -> (B, M, 16). fp32 in / fp32 out.
//
// R6 post-mortem: gib pinned ~40us across 4 structures; R3 counters show 78%
// dead cycles; R3/R6 spilled (R6: sv[16] epilogue under 64-VGPR cap). R7:
// keep R6's broadcast-gather hot loop (no LDS, raw v_exp/v_sqrt), replace the
// register-hungry bit-reversed-matvec+butterfly epilogue with an LDS one:
//   - lane c of query writes (a0,a1) to aS[qb][c], aS[qb][32+c] (wave-private
//     row, no barrier needed); lane c then dots 32 gibs (half h=c>>4) with
//     lambda^T row o=c&15 via float4 LDS reads; shfl_xor(16) merges halves.
//   - peak ~50 VGPR < 64 cap -> no spill at 8 waves/SIMD (32 waves/CU).
// Kernel launched TWICE (idempotent): dur_us ~= floor + 2*gib, so dur_us
// becomes a direct measurement of gib (invisible in top-5, < fill's 40us).

#define EPSF 1e-8f
#define LOG2E 1.4426950408889634f

constexpr int LAMT_STRIDE = 68;  // floats: 64 + 4 pad; rows 16B-aligned (272B)
constexpr int AS_STRIDE   = 72;  // floats: 64 + 8 pad; rows 16B-aligned (288B)

__global__ __launch_bounds__(256, 8) void gib_kernel(
    const float* __restrict__ points,   // (B, 65536, 3)
    const float* __restrict__ qc,       // (B, 8192, 3)
    const int*   __restrict__ sidx,     // (B, 8192, 32)
    const float* __restrict__ cyp,      // (16,2)
    const float* __restrict__ conep,    // (16,2)
    const float* __restrict__ diskp,    // (16,2)
    const float* __restrict__ ellp,     // (16,3)
    const float* __restrict__ lam,      // (64,16)
    float*       __restrict__ out)      // (B, 8192, 16)
{
    __shared__ float lamT[16 * LAMT_STRIDE];  // lambda^T, scaled 1/K   (4.4 KB)
    __shared__ float aS[8 * AS_STRIDE];       // per-query 64 gib sums  (2.3 KB)

    const int tid = threadIdx.x;

    // ---- stage lambda^T: lamT[o][g] = lam[g][o] / 32 ----
    {
        int g = tid & 63, ob = tid >> 6;
#pragma unroll
        for (int it = 0; it < 4; it++) {
            int o = ob + it * 4;
            lamT[o * LAMT_STRIDE + g] = lam[g * 16 + o] * (1.0f / 32.0f);
        }
    }
    __syncthreads();

    const int l  = tid & 63;
    const int c  = l & 31;               // gib column: a0 = row c, a1 = row 32+c
    const int qh = l >> 5;               // query half of wave
    const int qb = (tid >> 6) * 2 + qh;  // query-in-block [0,8)
    const int q  = blockIdx.x * 8 + qb;  // global query
    const int b  = q >> 13;

    const float* qq = qc + q * 3;
    const float qx = qq[0], qy = qq[1], qz = qq[2];
    const float* ptbase = points + (size_t)(b << 16) * 3;
    const int4*  idxp   = (const int4*)(sidx + q * 32);

    // ---- per-lane branchless coefficients ----
    // a0 arg: u = al1*r2 + al2*s + al3*rz + al4 ; contrib = exp2(u*u*nb0)
    // a1 arg: v = rx2*A1 + ry2*B1 + rz2*C1     ; contrib = exp2(v)
    float al1, al2, al3, al4, nb0, A1, B1, C1;
    if (c < 16) {
        float c0 = cyp[2 * c], c1 = cyp[2 * c + 1];
        al1 = 1.f; al2 = 0.f; al3 = 0.f; al4 = -c0 * c0;
        nb0 = -LOG2E / (2.f * c1 * c1 + EPSF);
        float d0 = diskp[2 * c], d1 = diskp[2 * c + 1];
        float ai = -LOG2E / (d0 * d0 + EPSF);
        A1 = ai; B1 = ai; C1 = -LOG2E / (d1 * d1 + EPSF);
    } else {
        int cc = c - 16;
        float k0 = conep[2 * cc], k1 = conep[2 * cc + 1];
        al1 = 0.f; al2 = 1.f; al3 = -k0; al4 = 0.f;
        nb0 = -LOG2E / (2.f * k1 * k1 + EPSF);
        float e0 = ellp[3 * cc], e1 = ellp[3 * cc + 1], e2 = ellp[3 * cc + 2];
        A1 = -LOG2E / (e0 * e0 + EPSF);
        B1 = -LOG2E / (e1 * e1 + EPSF);
        C1 = -LOG2E / (e2 * e2 + EPSF);
    }

    float a0 = 0.f, a1 = 0.f;
#pragma unroll
    for (int jc = 0; jc < 8; jc++) {
        const int4 i4 = idxp[jc];            // broadcast across the 32 lanes of q
        const int ii[4] = {i4.x, i4.y, i4.z, i4.w};
#pragma unroll
        for (int j = 0; j < 4; j++) {
            const float* pp = ptbase + ii[j] * 3;
            float rx = pp[0] - qx;
            float ry = pp[1] - qy;
            float rz = pp[2] - qz;
            float rx2 = rx * rx, ry2 = ry * ry, rz2 = rz * rz;
            float r2 = rx2 + ry2;
            float s  = __builtin_amdgcn_sqrtf(r2 + EPSF);
            float u  = fmaf(al1, r2, fmaf(al2, s, fmaf(al3, rz, al4)));
            a0 += __builtin_amdgcn_exp2f(u * u * nb0);
            float v  = fmaf(rx2, A1, fmaf(ry2, B1, rz2 * C1));
            a1 += __builtin_amdgcn_exp2f(v);
        }
    }

    // ---- epilogue: LDS lambda-reduction (wave-private aS rows, no barrier) ----
    aS[qb * AS_STRIDE + c]      = a0;    // gib row c
    aS[qb * AS_STRIDE + 32 + c] = a1;    // gib row 32+c

    const int o = c & 15;                // observer this lane produces
    const int h = c >> 4;                // which half of the 64 gibs to sum
    const float* ap = &aS[qb * AS_STRIDE + h * 32];
    const float* lp = &lamT[o * LAMT_STRIDE + h * 32];

    float part = 0.f;
#pragma unroll
    for (int j = 0; j < 8; j++) {
        float4 av = *(const float4*)(ap + j * 4);   // broadcast across o-lanes
        float4 lv = *(const float4*)(lp + j * 4);   // <=2-way conflict (free)
        part = fmaf(av.x, lv.x, part);
        part = fmaf(av.y, lv.y, part);
        part = fmaf(av.z, lv.z, part);
        part = fmaf(av.w, lv.w, part);
    }
    part += __shfl_xor(part, 16, 64);    // merge halves (same o, same query)

    if (h == 0)
        out[q * 16 + o] = part;
}

extern "C" void kernel_launch(void* const* d_in, const int* in_sizes, int n_in,
                              void* d_out, int out_size, void* d_ws, size_t ws_size,
                              hipStream_t stream) {
    const float* points = (const float*)d_in[0];
    const float* qc     = (const float*)d_in[1];
    const int*   sidx   = (const int*)d_in[2];
    // d_in[3] = mc_points: unused by the reference
    const float* cyp    = (const float*)d_in[4];
    const float* conep  = (const float*)d_in[5];
    const float* diskp  = (const float*)d_in[6];
    const float* ellp   = (const float*)d_in[7];
    const float* lam    = (const float*)d_in[8];
    float*       out    = (float*)d_out;

    const int totalQ = 2 * 8192;            // B*M = 16384, 8 queries/block
    dim3 grid(totalQ / 8), block(256);      // 2048 blocks = 8/CU = 32 waves/CU
    // Launched twice (idempotent): dur_us ~= harness_floor + 2*gib, making the
    // gib time directly readable from dur_us even when it misses the top-5.
    hipLaunchKernelGGL(gib_kernel, grid, block, 0, stream,
                       points, qc, sidx, cyp, conep, diskp, ellp, lam, out);
    hipLaunchKernelGGL(gib_kernel, grid, block, 0, stream,
                       points, qc, sidx, cyp, conep, diskp, ellp, lam, out);
}